// Round 6
// baseline (302.377 us; speedup 1.0000x reference)
//
#include <hip/hip_runtime.h>
#include <hip/hip_bf16.h>
#include <math.h>
#include <stdint.h>

#define B_DIM 2
#define S_DIM 2048
#define E_DIM 768
#define H_DIM 8
#define D_DIM 96
#define M_DIM (B_DIM*S_DIM)          // 4096
#define SCALE_F 0.10206207261596575f // 96^-0.5

typedef __bf16 bf16x8 __attribute__((ext_vector_type(8)));
typedef float  f32x4  __attribute__((ext_vector_type(4)));
typedef float  f32x16 __attribute__((ext_vector_type(16)));

#define MFMA16(a,b,c) __builtin_amdgcn_mfma_f32_16x16x32_bf16(a,b,c,0,0,0)
#define MFMA32(a,b,c) __builtin_amdgcn_mfma_f32_32x32x16_bf16(a,b,c,0,0,0)

__device__ inline void split_bf16(float f, unsigned short& h, unsigned short& l) {
    __bf16 hb = (__bf16)f;                 // RNE
    float  r  = f - (float)hb;             // exact residual
    __bf16 lb = (__bf16)r;
    h = __builtin_bit_cast(unsigned short, hb);
    l = __builtin_bit_cast(unsigned short, lb);
}

// CK-style async global->LDS, 16B per lane.
__device__ inline void gload16(const void* g, void* l) {
    auto gp = reinterpret_cast<const __attribute__((address_space(1))) uint32_t*>(
        reinterpret_cast<uintptr_t>(g));
    auto lp = reinterpret_cast<__attribute__((address_space(3))) uint32_t*>(
        reinterpret_cast<uintptr_t>(l));
    __builtin_amdgcn_global_load_lds(gp, lp, 16, 0, 0);
}

// ---------------------------------------------------------------------------
// x [4096,768] fp32 -> split bf16 hi/lo
// ---------------------------------------------------------------------------
__global__ __launch_bounds__(256) void convert_x_kernel(
    const float* __restrict__ X, unsigned short* __restrict__ Xh,
    unsigned short* __restrict__ Xl)
{
    int i = (blockIdx.x * 256 + threadIdx.x) * 4;
    float4 v = *(const float4*)(X + i);
    ushort4 h, l;
    split_bf16(v.x, h.x, l.x);
    split_bf16(v.y, h.y, l.y);
    split_bf16(v.z, h.z, l.z);
    split_bf16(v.w, h.w, l.w);
    *(ushort4*)(Xh + i) = h;
    *(ushort4*)(Xl + i) = l;
}

// ---------------------------------------------------------------------------
// All three W [768,768] fp32 [k][n] -> W^T bf16 [n][k], one launch (z = which)
// ---------------------------------------------------------------------------
__global__ __launch_bounds__(256) void convert_wT3_kernel(
    const float* __restrict__ W0, const float* __restrict__ W1,
    const float* __restrict__ W2,
    unsigned short* __restrict__ Th0, unsigned short* __restrict__ Tl0,
    unsigned short* __restrict__ Th1, unsigned short* __restrict__ Tl1,
    unsigned short* __restrict__ Th2)
{
    const float* W; unsigned short *Th, *Tl;
    if (blockIdx.z == 0)      { W = W0; Th = Th0; Tl = Tl0; }
    else if (blockIdx.z == 1) { W = W1; Th = Th1; Tl = Tl1; }
    else                      { W = W2; Th = Th2; Tl = nullptr; }

    __shared__ float tile[64][65];
    const int tid = threadIdx.x;
    const int k0 = blockIdx.y << 6, n0 = blockIdx.x << 6;
    const int r = tid >> 4, c4 = (tid & 15) << 2;
    #pragma unroll
    for (int i = 0; i < 4; ++i) {
        float4 v = *(const float4*)(W + (size_t)(k0 + r + i*16)*E_DIM + n0 + c4);
        tile[r + i*16][c4+0] = v.x; tile[r + i*16][c4+1] = v.y;
        tile[r + i*16][c4+2] = v.z; tile[r + i*16][c4+3] = v.w;
    }
    __syncthreads();
    #pragma unroll
    for (int i = 0; i < 4; ++i) {
        int n = r + i*16;
        ushort4 h, l;
        split_bf16(tile[c4+0][n], h.x, l.x);
        split_bf16(tile[c4+1][n], h.y, l.y);
        split_bf16(tile[c4+2][n], h.z, l.z);
        split_bf16(tile[c4+3][n], h.w, l.w);
        *(ushort4*)(Th + (size_t)(n0 + n)*E_DIM + k0 + c4) = h;
        if (Tl) *(ushort4*)(Tl + (size_t)(n0 + n)*E_DIM + k0 + c4) = l;
    }
}

// ---------------------------------------------------------------------------
// Fused Q/K projection, split-bf16 (3 MFMA passes). Unchanged from R2.
// ---------------------------------------------------------------------------
__global__ __launch_bounds__(256) void gemm_qk_kernel(
    const unsigned short* __restrict__ Ah, const unsigned short* __restrict__ Al,
    const unsigned short* __restrict__ Bh, const unsigned short* __restrict__ Bl,
    const float* __restrict__ bq, const float* __restrict__ bk,
    unsigned short* __restrict__ Qh, unsigned short* __restrict__ Ql,
    unsigned short* __restrict__ Kh, unsigned short* __restrict__ Kl)
{
    __shared__ unsigned short sAh[128*32], sAl[128*32];
    __shared__ unsigned short sBh[128*32], sBl[128*32];

    const int tid  = threadIdx.x;
    const int lane = tid & 63;
    const int w    = tid >> 6;
    const int qn   = lane & 15, quad = lane >> 4;
    const int wm   = w & 1, wn = w >> 1;
    const int row0 = blockIdx.y << 7;
    const int col0 = blockIdx.x << 7;

    const int sr = tid >> 2;
    const int sk = (tid & 3) << 3;

    const unsigned short* gAh = Ah + (size_t)(row0 + sr)*E_DIM + sk;
    const unsigned short* gAl = Al + (size_t)(row0 + sr)*E_DIM + sk;
    const unsigned short* gBh = Bh + (size_t)(col0 + sr)*E_DIM + sk;
    const unsigned short* gBl = Bl + (size_t)(col0 + sr)*E_DIM + sk;

    f32x4 acc[4][4];
    #pragma unroll
    for (int mt = 0; mt < 4; ++mt)
        #pragma unroll
        for (int nt = 0; nt < 4; ++nt)
            { acc[mt][nt][0]=0.f; acc[mt][nt][1]=0.f; acc[mt][nt][2]=0.f; acc[mt][nt][3]=0.f; }

    for (int k0 = 0; k0 < E_DIM; k0 += 32) {
        __syncthreads();
        gload16(gAh + k0,              sAh + tid*8);
        gload16(gAh + 64*E_DIM + k0,   sAh + 2048 + tid*8);
        gload16(gAl + k0,              sAl + tid*8);
        gload16(gAl + 64*E_DIM + k0,   sAl + 2048 + tid*8);
        gload16(gBh + k0,              sBh + tid*8);
        gload16(gBh + 64*E_DIM + k0,   sBh + 2048 + tid*8);
        gload16(gBl + k0,              sBl + tid*8);
        gload16(gBl + 64*E_DIM + k0,   sBl + 2048 + tid*8);
        __syncthreads();

        bf16x8 afh[4], afl[4], bfh[4], bfl[4];
        #pragma unroll
        for (int mt = 0; mt < 4; ++mt) {
            int m = wm*64 + mt*16 + qn;
            afh[mt] = *(const bf16x8*)&sAh[m*32 + quad*8];
            afl[mt] = *(const bf16x8*)&sAl[m*32 + quad*8];
        }
        #pragma unroll
        for (int nt = 0; nt < 4; ++nt) {
            int n = wn*64 + nt*16 + qn;
            bfh[nt] = *(const bf16x8*)&sBh[n*32 + quad*8];
            bfl[nt] = *(const bf16x8*)&sBl[n*32 + quad*8];
        }
        #pragma unroll
        for (int mt = 0; mt < 4; ++mt)
            #pragma unroll
            for (int nt = 0; nt < 4; ++nt) {
                acc[mt][nt] = MFMA16(afh[mt], bfh[nt], acc[mt][nt]);
                acc[mt][nt] = MFMA16(afh[mt], bfl[nt], acc[mt][nt]);
                acc[mt][nt] = MFMA16(afl[mt], bfh[nt], acc[mt][nt]);
            }
    }

    #pragma unroll
    for (int nt = 0; nt < 4; ++nt) {
        int n = col0 + wn*64 + nt*16 + qn;
        bool isQ = n < E_DIM;
        float bias = isQ ? bq[n] : bk[n - E_DIM];
        unsigned short* oh = isQ ? Qh : Kh;
        unsigned short* ol = isQ ? Ql : Kl;
        int nc = isQ ? n : n - E_DIM;
        #pragma unroll
        for (int mt = 0; mt < 4; ++mt)
            #pragma unroll
            for (int r = 0; r < 4; ++r) {
                int m = row0 + wm*64 + mt*16 + quad*4 + r;
                unsigned short hh, ll;
                split_bf16(acc[mt][nt][r] + bias, hh, ll);
                oh[(size_t)m*E_DIM + nc] = hh;
                ol[(size_t)m*E_DIM + nc] = ll;
            }
    }
}

// ---------------------------------------------------------------------------
// Output projection, plain bf16. Unchanged from R2.
// ---------------------------------------------------------------------------
__global__ __launch_bounds__(256) void gemm_out_kernel(
    const unsigned short* __restrict__ A, const unsigned short* __restrict__ Bt,
    const float* __restrict__ bo, float* __restrict__ out)
{
    __shared__ unsigned short sA[128*32];
    __shared__ unsigned short sB[128*32];

    const int tid  = threadIdx.x;
    const int lane = tid & 63;
    const int w    = tid >> 6;
    const int qn   = lane & 15, quad = lane >> 4;
    const int wm   = w & 1, wn = w >> 1;
    const int row0 = blockIdx.y << 7;
    const int col0 = blockIdx.x << 7;

    const int sr = tid >> 2;
    const int sk = (tid & 3) << 3;

    const unsigned short* gA = A  + (size_t)(row0 + sr)*E_DIM + sk;
    const unsigned short* gB = Bt + (size_t)(col0 + sr)*E_DIM + sk;

    f32x4 acc[4][4];
    #pragma unroll
    for (int mt = 0; mt < 4; ++mt)
        #pragma unroll
        for (int nt = 0; nt < 4; ++nt)
            { acc[mt][nt][0]=0.f; acc[mt][nt][1]=0.f; acc[mt][nt][2]=0.f; acc[mt][nt][3]=0.f; }

    for (int k0 = 0; k0 < E_DIM; k0 += 32) {
        __syncthreads();
        gload16(gA + k0,            sA + tid*8);
        gload16(gA + 64*E_DIM + k0, sA + 2048 + tid*8);
        gload16(gB + k0,            sB + tid*8);
        gload16(gB + 64*E_DIM + k0, sB + 2048 + tid*8);
        __syncthreads();

        bf16x8 af[4], bf[4];
        #pragma unroll
        for (int mt = 0; mt < 4; ++mt)
            af[mt] = *(const bf16x8*)&sA[(wm*64 + mt*16 + qn)*32 + quad*8];
        #pragma unroll
        for (int nt = 0; nt < 4; ++nt)
            bf[nt] = *(const bf16x8*)&sB[(wn*64 + nt*16 + qn)*32 + quad*8];
        #pragma unroll
        for (int mt = 0; mt < 4; ++mt)
            #pragma unroll
            for (int nt = 0; nt < 4; ++nt)
                acc[mt][nt] = MFMA16(af[mt], bf[nt], acc[mt][nt]);
    }

    #pragma unroll
    for (int nt = 0; nt < 4; ++nt) {
        int n = col0 + wn*64 + nt*16 + qn;
        float bias = bo[n];
        #pragma unroll
        for (int mt = 0; mt < 4; ++mt)
            #pragma unroll
            for (int r = 0; r < 4; ++r) {
                int m = row0 + wm*64 + mt*16 + quad*4 + r;
                out[(size_t)m*E_DIM + n] = acc[mt][nt][r] + bias;
            }
    }
}

// ---------------------------------------------------------------------------
// Flash attention v4: 32x32x16 MFMA, 256 thr = 4 waves, q-tile 128,
// key-split x4 (512 keys / block, 8 iters of 64).
// QK^T A-frags (K hi/lo) read DIRECTLY from global (L1/L2-resident) — no
// sKh/sKl staging. LDS = double-buffered sKt (V^T for PV) + sPs only; ONE
// barrier per iteration (dbuf Kt, sPs wave-private).
// ---------------------------------------------------------------------------
__global__ __launch_bounds__(256) void attn_mfma_kernel(
    const unsigned short* __restrict__ Qh, const unsigned short* __restrict__ Ql,
    const unsigned short* __restrict__ Kh, const unsigned short* __restrict__ Kl,
    unsigned short* __restrict__ O0, unsigned short* __restrict__ O1,
    unsigned short* __restrict__ O2, unsigned short* __restrict__ O3,
    float2* __restrict__ ml)
{
    __shared__ unsigned short sKt[2][96][72];  // [buf][e][key]
    __shared__ unsigned short sPs[128][72];    // [q][key]

    const int tid  = threadIdx.x;
    const int w    = tid >> 6;       // wave 0..3: q rows [w*32, w*32+32)
    const int lane = tid & 63;
    const int col  = lane & 31;      // fragment row/col index
    const int half = lane >> 5;      // k-half selector
    const int z    = blockIdx.z;
    const int b    = z >> 2;
    const int kv   = z & 3;          // key quarter
    const int h    = blockIdx.y;
    const int q0   = blockIdx.x << 7;
    const int key0 = kv << 9;        // kv*512

    // Q B-frags: B[k=d][n=q], lane reads 8 contiguous d at row q=col
    bf16x8 qhf[6], qlf[6];
    {
        const size_t ro = ((size_t)(b*S_DIM + q0 + w*32 + col))*E_DIM
                          + h*D_DIM + half*8;
        #pragma unroll
        for (int kc = 0; kc < 6; ++kc) {
            qhf[kc] = *(const bf16x8*)(Qh + ro + kc*16);
            qlf[kc] = *(const bf16x8*)(Ql + ro + kc*16);
        }
    }

    f32x16 o[3];
    #pragma unroll
    for (int nt = 0; nt < 3; ++nt)
        #pragma unroll
        for (int r = 0; r < 16; ++r) o[nt][r] = 0.f;
    float m_i = -INFINITY, l_i = 0.f;

    // Kt staging mapping: thread -> key rows {jr, jr+1}, e range [dc, dc+12)
    const int jr = (tid >> 3) << 1;  // 0..62
    const int dc = (tid & 7) * 12;   // 0..84

    // prefetch key-tile 0 rows for Kt
    ushort4 p0[3], p1[3];
    {
        const size_t g0 = ((size_t)(b*S_DIM + key0 + jr))*E_DIM + h*D_DIM + dc;
        #pragma unroll
        for (int i = 0; i < 3; ++i) {
            p0[i] = *(const ushort4*)(Kh + g0 + 4*i);
            p1[i] = *(const ushort4*)(Kh + g0 + E_DIM + 4*i);
        }
    }

    const size_t kbase = ((size_t)(b*S_DIM + key0))*E_DIM + h*D_DIM;

    for (int kt = 0; kt < 8; ++kt) {
        const int buf = kt & 1;
        // ---- write V^T tile (from prefetched regs) ----
        {
            const unsigned short* q0p = (const unsigned short*)p0;
            const unsigned short* q1p = (const unsigned short*)p1;
            #pragma unroll
            for (int c = 0; c < 12; ++c) {
                unsigned int pk = (unsigned int)q0p[c] | ((unsigned int)q1p[c] << 16);
                *(unsigned int*)&sKt[buf][dc + c][jr] = pk;
            }
        }
        __syncthreads();   // Kt[buf] visible; prev iter's reads all done

        // prefetch next Kt tile (lands during this iter's compute)
        if (kt + 1 < 8) {
            const size_t g0 = kbase + (size_t)(kt+1)*64*E_DIM + (size_t)jr*E_DIM + dc;
            #pragma unroll
            for (int i = 0; i < 3; ++i) {
                p0[i] = *(const ushort4*)(Kh + g0 + 4*i);
                p1[i] = *(const ushort4*)(Kh + g0 + E_DIM + 4*i);
            }
        }

        // ---- S^T = K·Q^T (split-bf16), K-frags straight from global ----
        f32x16 s[2];
        #pragma unroll
        for (int mt = 0; mt < 2; ++mt) {
            const size_t arow = kbase + (size_t)(kt*64 + mt*32 + col)*E_DIM + half*8;
            f32x16 acc;
            #pragma unroll
            for (int r = 0; r < 16; ++r) acc[r] = 0.f;
            #pragma unroll
            for (int kc = 0; kc < 6; ++kc) {
                bf16x8 ah = *(const bf16x8*)(Kh + arow + kc*16);
                bf16x8 al = *(const bf16x8*)(Kl + arow + kc*16);
                acc = MFMA32(ah, qhf[kc], acc);
                acc = MFMA32(ah, qlf[kc], acc);
                acc = MFMA32(al, qhf[kc], acc);
            }
            s[mt] = acc;
        }

        // ---- online softmax, per-lane state (q = col) ----
        float mx = s[0][0];
        #pragma unroll
        for (int mt = 0; mt < 2; ++mt)
            #pragma unroll
            for (int r = 0; r < 16; ++r) mx = fmaxf(mx, s[mt][r]);
        mx = fmaxf(mx, __shfl_xor(mx, 32));

        float m_new = fmaxf(m_i, mx);
        float alpha = __expf(m_i - m_new);
        m_i = m_new;

        float psum = 0.f;
        #pragma unroll
        for (int mt = 0; mt < 2; ++mt)
            #pragma unroll
            for (int g = 0; g < 4; ++g) {
                float e0 = __expf(s[mt][4*g+0] - m_new);
                float e1 = __expf(s[mt][4*g+1] - m_new);
                float e2 = __expf(s[mt][4*g+2] - m_new);
                float e3 = __expf(s[mt][4*g+3] - m_new);
                psum += e0 + e1 + e2 + e3;
                ushort4 pk;
                pk.x = __builtin_bit_cast(unsigned short, (__bf16)e0);
                pk.y = __builtin_bit_cast(unsigned short, (__bf16)e1);
                pk.z = __builtin_bit_cast(unsigned short, (__bf16)e2);
                pk.w = __builtin_bit_cast(unsigned short, (__bf16)e3);
                *(ushort4*)&sPs[w*32 + col][mt*32 + 8*g + 4*half] = pk;
            }
        psum += __shfl_xor(psum, 32);
        l_i = l_i * alpha + psum;

        // rescale O: row q_r = 8g + r + 4*half; state lives at lane q_r
        #pragma unroll
        for (int g = 0; g < 4; ++g)
            #pragma unroll
            for (int r = 0; r < 4; ++r) {
                float ar = __shfl(alpha, 8*g + r + 4*half);
                #pragma unroll
                for (int nt = 0; nt < 3; ++nt) o[nt][4*g + r] *= ar;
            }

        // ---- PV: Ohat[q][e] += P·V (A = own sPs rows, B = sKt[buf]) ----
        #pragma unroll
        for (int kc = 0; kc < 4; ++kc) {
            bf16x8 pa = *(const bf16x8*)&sPs[w*32 + col][kc*16 + half*8];
            #pragma unroll
            for (int nt = 0; nt < 3; ++nt) {
                bf16x8 vb = *(const bf16x8*)&sKt[buf][nt*32 + col][kc*16 + half*8];
                o[nt] = MFMA32(pa, vb, o[nt]);
            }
        }
    }

    // ---- epilogue: unnormalized Ohat (fp16) + per-row (m,l) ----
    unsigned short* Ob = (kv == 0 ? O0 : kv == 1 ? O1 : kv == 2 ? O2 : O3)
        + ((size_t)(b*S_DIM + q0 + w*32))*E_DIM + h*D_DIM;
    #pragma unroll
    for (int g = 0; g < 4; ++g)
        #pragma unroll
        for (int r = 0; r < 4; ++r) {
            int qr = 8*g + r + 4*half;
            #pragma unroll
            for (int nt = 0; nt < 3; ++nt) {
                _Float16 hv = (_Float16)o[nt][4*g + r];
                Ob[(size_t)qr*E_DIM + nt*32 + col] =
                    __builtin_bit_cast(unsigned short, hv);
            }
        }
    if (lane < 32) {
        int q = q0 + w*32 + lane;
        ml[((size_t)(kv*B_DIM + b)*H_DIM + h)*S_DIM + q] = make_float2(m_i, l_i);
    }
}

// ---------------------------------------------------------------------------
// Merge the four key-quarter partials -> bf16 context (SCALE applied here)
// ---------------------------------------------------------------------------
__global__ __launch_bounds__(256) void combine_kernel(
    const unsigned short* __restrict__ O0, const unsigned short* __restrict__ O1,
    const unsigned short* __restrict__ O2, const unsigned short* __restrict__ O3,
    const float2* __restrict__ ml, unsigned short* __restrict__ AObf)
{
    size_t idx = ((size_t)blockIdx.x * 256 + threadIdx.x) * 4;
    int row = (int)(idx / E_DIM);
    int ce  = (int)(idx % E_DIM);
    int h   = ce / D_DIM;
    int b   = row >> 11;
    int q   = row & (S_DIM - 1);

    float2 mv[4];
    #pragma unroll
    for (int s = 0; s < 4; ++s)
        mv[s] = ml[((size_t)(s*B_DIM + b)*H_DIM + h)*S_DIM + q];
    float m = fmaxf(fmaxf(mv[0].x, mv[1].x), fmaxf(mv[2].x, mv[3].x));
    float wq[4], l = 0.f;
    #pragma unroll
    for (int s = 0; s < 4; ++s) { wq[s] = __expf(mv[s].x - m); l += mv[s].y * wq[s]; }
    float inv = SCALE_F / l;
    #pragma unroll
    for (int s = 0; s < 4; ++s) wq[s] *= inv;

    ushort4 a0 = *(const ushort4*)(O0 + idx);
    ushort4 a1 = *(const ushort4*)(O1 + idx);
    ushort4 a2 = *(const ushort4*)(O2 + idx);
    ushort4 a3 = *(const ushort4*)(O3 + idx);
    float v[4];
    v[0] = (float)__builtin_bit_cast(_Float16, a0.x)*wq[0] + (float)__builtin_bit_cast(_Float16, a1.x)*wq[1]
         + (float)__builtin_bit_cast(_Float16, a2.x)*wq[2] + (float)__builtin_bit_cast(_Float16, a3.x)*wq[3];
    v[1] = (float)__builtin_bit_cast(_Float16, a0.y)*wq[0] + (float)__builtin_bit_cast(_Float16, a1.y)*wq[1]
         + (float)__builtin_bit_cast(_Float16, a2.y)*wq[2] + (float)__builtin_bit_cast(_Float16, a3.y)*wq[3];
    v[2] = (float)__builtin_bit_cast(_Float16, a0.z)*wq[0] + (float)__builtin_bit_cast(_Float16, a1.z)*wq[1]
         + (float)__builtin_bit_cast(_Float16, a2.z)*wq[2] + (float)__builtin_bit_cast(_Float16, a3.z)*wq[3];
    v[3] = (float)__builtin_bit_cast(_Float16, a0.w)*wq[0] + (float)__builtin_bit_cast(_Float16, a1.w)*wq[1]
         + (float)__builtin_bit_cast(_Float16, a2.w)*wq[2] + (float)__builtin_bit_cast(_Float16, a3.w)*wq[3];
    ushort4 o;
    o.x = __builtin_bit_cast(unsigned short, (__bf16)v[0]);
    o.y = __builtin_bit_cast(unsigned short, (__bf16)v[1]);
    o.z = __builtin_bit_cast(unsigned short, (__bf16)v[2]);
    o.w = __builtin_bit_cast(unsigned short, (__bf16)v[3]);
    *(ushort4*)(AObf + idx) = o;
}

// ---------------------------------------------------------------------------
extern "C" void kernel_launch(void* const* d_in, const int* in_sizes, int n_in,
                              void* d_out, int out_size, void* d_ws, size_t ws_size,
                              hipStream_t stream)
{
    const float* x  = (const float*)d_in[0];
    const float* Wq = (const float*)d_in[1];
    const float* bq = (const float*)d_in[2];
    const float* Wk = (const float*)d_in[3];
    const float* bk = (const float*)d_in[4];
    const float* Wo = (const float*)d_in[5];
    const float* bo = (const float*)d_in[6];
    float* out = (float*)d_out;

    const size_t NE = (size_t)M_DIM * E_DIM;        // 3.1M elems
    const size_t WE = (size_t)E_DIM * E_DIM;        // 590K elems
    unsigned short* xh    = (unsigned short*)d_ws;
    unsigned short* xl    = xh + NE;
    unsigned short* WqkTh = xl + NE;
    unsigned short* WqkTl = WqkTh + 2*WE;
    unsigned short* WoTh  = WqkTl + 2*WE;
    unsigned short* Qh    = WoTh + WE;
    unsigned short* Ql    = Qh + NE;
    unsigned short* Kh    = Ql + NE;
    unsigned short* Kl    = Kh + NE;
    unsigned short* AObf  = Kl + NE;
    float2*         mlbuf = (float2*)(AObf + NE);   // 4*B*H*S float2 = 1 MB
    unsigned short* Oh0   = xh;                     // alias: x dead after gemm_qk
    unsigned short* Oh1   = xl;
    unsigned short* Oh2   = (unsigned short*)d_out; // overwritten by gemm_out later
    unsigned short* Oh3   = Oh2 + NE;

    dim3 blk(256);
    hipLaunchKernelGGL(convert_x_kernel, dim3(NE/1024), blk, 0, stream, x, xh, xl);
    hipLaunchKernelGGL(convert_wT3_kernel, dim3(12,12,3), blk, 0, stream,
                       Wq, Wk, Wo, WqkTh, WqkTl, WqkTh + WE, WqkTl + WE, WoTh);

    hipLaunchKernelGGL(gemm_qk_kernel, dim3(12,32), blk, 0, stream,
                       xh, xl, WqkTh, WqkTl, bq, bk, Qh, Ql, Kh, Kl);

    hipLaunchKernelGGL(attn_mfma_kernel, dim3(S_DIM/128, H_DIM, B_DIM*4), blk, 0,
                       stream, Qh, Ql, Kh, Kl, Oh0, Oh1, Oh2, Oh3, mlbuf);

    hipLaunchKernelGGL(combine_kernel, dim3(NE/1024), blk, 0, stream,
                       Oh0, Oh1, Oh2, Oh3, mlbuf, AObf);

    hipLaunchKernelGGL(gemm_out_kernel, dim3(6,32), blk, 0, stream,
                       AObf, WoTh, bo, out);
}

// Round 7
// 168.300 us; speedup vs baseline: 1.7967x; 1.7967x over previous
//
#include <hip/hip_runtime.h>
#include <hip/hip_bf16.h>
#include <math.h>
#include <stdint.h>

#define B_DIM 2
#define S_DIM 2048
#define E_DIM 768
#define H_DIM 8
#define D_DIM 96
#define M_DIM (B_DIM*S_DIM)          // 4096
#define SCALE_F 0.10206207261596575f // 96^-0.5

typedef _Float16 f16x8 __attribute__((ext_vector_type(8)));
typedef float    f32x4  __attribute__((ext_vector_type(4)));
typedef float    f32x16 __attribute__((ext_vector_type(16)));

#define MFMA16H(a,b,c) __builtin_amdgcn_mfma_f32_16x16x32_f16(a,b,c,0,0,0)
#define MFMA32H(a,b,c) __builtin_amdgcn_mfma_f32_32x32x16_f16(a,b,c,0,0,0)

__device__ inline unsigned short f2h(float f) {
    return __builtin_bit_cast(unsigned short, (_Float16)f);
}

// CK-style async global->LDS, 16B per lane.
__device__ inline void gload16(const void* g, void* l) {
    auto gp = reinterpret_cast<const __attribute__((address_space(1))) uint32_t*>(
        reinterpret_cast<uintptr_t>(g));
    auto lp = reinterpret_cast<__attribute__((address_space(3))) uint32_t*>(
        reinterpret_cast<uintptr_t>(l));
    __builtin_amdgcn_global_load_lds(gp, lp, 16, 0, 0);
}

// ---------------------------------------------------------------------------
// x [4096,768] fp32 -> fp16
// ---------------------------------------------------------------------------
__global__ __launch_bounds__(256) void convert_x_kernel(
    const float* __restrict__ X, unsigned short* __restrict__ Xf)
{
    int i = (blockIdx.x * 256 + threadIdx.x) * 4;
    float4 v = *(const float4*)(X + i);
    ushort4 h;
    h.x = f2h(v.x); h.y = f2h(v.y); h.z = f2h(v.z); h.w = f2h(v.w);
    *(ushort4*)(Xf + i) = h;
}

// ---------------------------------------------------------------------------
// All three W [768,768] fp32 [k][n] -> W^T fp16 [n][k], one launch (z = which)
// ---------------------------------------------------------------------------
__global__ __launch_bounds__(256) void convert_wT3_kernel(
    const float* __restrict__ W0, const float* __restrict__ W1,
    const float* __restrict__ W2,
    unsigned short* __restrict__ T0, unsigned short* __restrict__ T1,
    unsigned short* __restrict__ T2)
{
    const float* W; unsigned short* T;
    if (blockIdx.z == 0)      { W = W0; T = T0; }
    else if (blockIdx.z == 1) { W = W1; T = T1; }
    else                      { W = W2; T = T2; }

    __shared__ float tile[64][65];
    const int tid = threadIdx.x;
    const int k0 = blockIdx.y << 6, n0 = blockIdx.x << 6;
    const int r = tid >> 4, c4 = (tid & 15) << 2;
    #pragma unroll
    for (int i = 0; i < 4; ++i) {
        float4 v = *(const float4*)(W + (size_t)(k0 + r + i*16)*E_DIM + n0 + c4);
        tile[r + i*16][c4+0] = v.x; tile[r + i*16][c4+1] = v.y;
        tile[r + i*16][c4+2] = v.z; tile[r + i*16][c4+3] = v.w;
    }
    __syncthreads();
    #pragma unroll
    for (int i = 0; i < 4; ++i) {
        int n = r + i*16;
        ushort4 h;
        h.x = f2h(tile[c4+0][n]); h.y = f2h(tile[c4+1][n]);
        h.z = f2h(tile[c4+2][n]); h.w = f2h(tile[c4+3][n]);
        *(ushort4*)(T + (size_t)(n0 + n)*E_DIM + k0 + c4) = h;
    }
}

// ---------------------------------------------------------------------------
// Fused Q/K projection, plain fp16 (1 MFMA pass):
//   C[m,n] = A·B^T + bias; A = x fp16, B^T = [Wq|Wk]^T fp16 [n][k].
// 128x128 tile, BK=32, 4 waves (2x2 of 64x64), global_load_lds staging.
// ---------------------------------------------------------------------------
__global__ __launch_bounds__(256) void gemm_qk_kernel(
    const unsigned short* __restrict__ A, const unsigned short* __restrict__ Bt,
    const float* __restrict__ bq, const float* __restrict__ bk,
    unsigned short* __restrict__ Qf, unsigned short* __restrict__ Kf)
{
    __shared__ unsigned short sA[128*32];
    __shared__ unsigned short sB[128*32];

    const int tid  = threadIdx.x;
    const int lane = tid & 63;
    const int w    = tid >> 6;
    const int qn   = lane & 15, quad = lane >> 4;
    const int wm   = w & 1, wn = w >> 1;
    const int row0 = blockIdx.y << 7;
    const int col0 = blockIdx.x << 7;   // 0..1408 (Q: <768, K: >=768)

    const int sr = tid >> 2;            // 0..63
    const int sk = (tid & 3) << 3;      // 0,8,16,24

    const unsigned short* gA = A  + (size_t)(row0 + sr)*E_DIM + sk;
    const unsigned short* gB = Bt + (size_t)(col0 + sr)*E_DIM + sk;

    f32x4 acc[4][4];
    #pragma unroll
    for (int mt = 0; mt < 4; ++mt)
        #pragma unroll
        for (int nt = 0; nt < 4; ++nt)
            { acc[mt][nt][0]=0.f; acc[mt][nt][1]=0.f; acc[mt][nt][2]=0.f; acc[mt][nt][3]=0.f; }

    for (int k0 = 0; k0 < E_DIM; k0 += 32) {
        __syncthreads();
        gload16(gA + k0,            sA + tid*8);
        gload16(gA + 64*E_DIM + k0, sA + 2048 + tid*8);
        gload16(gB + k0,            sB + tid*8);
        gload16(gB + 64*E_DIM + k0, sB + 2048 + tid*8);
        __syncthreads();

        f16x8 af[4], bf[4];
        #pragma unroll
        for (int mt = 0; mt < 4; ++mt)
            af[mt] = *(const f16x8*)&sA[(wm*64 + mt*16 + qn)*32 + quad*8];
        #pragma unroll
        for (int nt = 0; nt < 4; ++nt)
            bf[nt] = *(const f16x8*)&sB[(wn*64 + nt*16 + qn)*32 + quad*8];
        #pragma unroll
        for (int mt = 0; mt < 4; ++mt)
            #pragma unroll
            for (int nt = 0; nt < 4; ++nt)
                acc[mt][nt] = MFMA16H(af[mt], bf[nt], acc[mt][nt]);
    }

    #pragma unroll
    for (int nt = 0; nt < 4; ++nt) {
        int n = col0 + wn*64 + nt*16 + qn;
        bool isQ = n < E_DIM;
        float bias = isQ ? bq[n] : bk[n - E_DIM];
        unsigned short* op = isQ ? Qf : Kf;
        int nc = isQ ? n : n - E_DIM;
        #pragma unroll
        for (int mt = 0; mt < 4; ++mt)
            #pragma unroll
            for (int r = 0; r < 4; ++r) {
                int m = row0 + wm*64 + mt*16 + quad*4 + r;
                op[(size_t)m*E_DIM + nc] = f2h(acc[mt][nt][r] + bias);
            }
    }
}

// ---------------------------------------------------------------------------
// Output projection fp16: out[m,n] = ctx·Wo^T + bo (fp32 out).
// 128x64 tile (384 blocks for 256 CUs), BK=32, 4 waves 2x2 of 64x32.
// ---------------------------------------------------------------------------
__global__ __launch_bounds__(256) void gemm_out_kernel(
    const unsigned short* __restrict__ A, const unsigned short* __restrict__ Bt,
    const float* __restrict__ bo, float* __restrict__ out)
{
    __shared__ unsigned short sA[128*32];
    __shared__ unsigned short sB[64*32];

    const int tid  = threadIdx.x;
    const int lane = tid & 63;
    const int w    = tid >> 6;
    const int qn   = lane & 15, quad = lane >> 4;
    const int wm   = w & 1, wn = w >> 1;
    const int row0 = blockIdx.y << 7;
    const int col0 = blockIdx.x << 6;

    const int sr = tid >> 2;            // 0..63
    const int sk = (tid & 3) << 3;

    const unsigned short* gA = A  + (size_t)(row0 + sr)*E_DIM + sk;
    const unsigned short* gB = Bt + (size_t)(col0 + sr)*E_DIM + sk;

    f32x4 acc[4][2];
    #pragma unroll
    for (int mt = 0; mt < 4; ++mt)
        #pragma unroll
        for (int nt = 0; nt < 2; ++nt)
            { acc[mt][nt][0]=0.f; acc[mt][nt][1]=0.f; acc[mt][nt][2]=0.f; acc[mt][nt][3]=0.f; }

    for (int k0 = 0; k0 < E_DIM; k0 += 32) {
        __syncthreads();
        gload16(gA + k0,            sA + tid*8);
        gload16(gA + 64*E_DIM + k0, sA + 2048 + tid*8);
        gload16(gB + k0,            sB + tid*8);
        __syncthreads();

        f16x8 af[4], bf[2];
        #pragma unroll
        for (int mt = 0; mt < 4; ++mt)
            af[mt] = *(const f16x8*)&sA[(wm*64 + mt*16 + qn)*32 + quad*8];
        #pragma unroll
        for (int nt = 0; nt < 2; ++nt)
            bf[nt] = *(const f16x8*)&sB[(wn*32 + nt*16 + qn)*32 + quad*8];
        #pragma unroll
        for (int mt = 0; mt < 4; ++mt)
            #pragma unroll
            for (int nt = 0; nt < 2; ++nt)
                acc[mt][nt] = MFMA16H(af[mt], bf[nt], acc[mt][nt]);
    }

    #pragma unroll
    for (int nt = 0; nt < 2; ++nt) {
        int n = col0 + wn*32 + nt*16 + qn;
        float bias = bo[n];
        #pragma unroll
        for (int mt = 0; mt < 4; ++mt)
            #pragma unroll
            for (int r = 0; r < 4; ++r) {
                int m = row0 + wm*64 + mt*16 + quad*4 + r;
                out[(size_t)m*E_DIM + n] = acc[mt][nt][r] + bias;
            }
    }
}

// ---------------------------------------------------------------------------
// Flash attention v5 (fp16): 32x32x16 MFMA, 256 thr = 4 waves, q-tile 128,
// key-split x2 (1024 keys / block, 16 iters of 64). R4's proven LDS staging
// structure; only K_hi exists now (plain fp16), staged by threads 0-127.
// S^T = K·Q^T (1 MFMA per frag pair), per-lane softmax (q = col),
// P fp16 -> sPs (PV A-layout), PV from transposed sKt. Unnormalized fp16
// Ohat partials + (m,l); combine merges.
// ---------------------------------------------------------------------------
__global__ __launch_bounds__(256) void attn_mfma_kernel(
    const unsigned short* __restrict__ Qf, const unsigned short* __restrict__ Kf,
    unsigned short* __restrict__ O0, unsigned short* __restrict__ O1,
    float2* __restrict__ ml)
{
    __shared__ unsigned short sKh[64][104];  // [key][d]
    __shared__ unsigned short sKt[96][72];   // [e][key]
    __shared__ unsigned short sPs[128][72];  // [q][key]

    const int tid  = threadIdx.x;
    const int w    = tid >> 6;       // wave 0..3: q rows [w*32, w*32+32)
    const int lane = tid & 63;
    const int col  = lane & 31;      // fragment row/col index
    const int half = lane >> 5;      // k-half selector
    const int b    = blockIdx.z >> 1;
    const int kh   = blockIdx.z & 1; // key half
    const int h    = blockIdx.y;
    const int q0   = blockIdx.x << 7;
    const int key0 = kh << 10;       // 0 or 1024

    // Q B-frags: B[k=d][n=q], lane reads 8 contiguous d at row q=col
    f16x8 qf[6];
    {
        const size_t ro = ((size_t)(b*S_DIM + q0 + w*32 + col))*E_DIM
                          + h*D_DIM + half*8;
        #pragma unroll
        for (int kc = 0; kc < 6; ++kc)
            qf[kc] = *(const f16x8*)(Qf + ro + kc*16);
    }

    f32x16 o[3];
    #pragma unroll
    for (int nt = 0; nt < 3; ++nt)
        #pragma unroll
        for (int r = 0; r < 16; ++r) o[nt][r] = 0.f;
    float m_i = -INFINITY, l_i = 0.f;

    // staging (threads 0-127): rows {2sp, 2sp+1}, d range [dq*24, dq*24+24)
    const bool stager = tid < 128;
    const int st = tid & 127;
    const int sp = st >> 2;          // 0..31
    const int dq = st & 3;           // 0..3

    uint4 r0[3], r1[3];
    if (stager) {
        const size_t g0 = ((size_t)(b*S_DIM + key0 + 2*sp))*E_DIM + h*D_DIM + dq*24;
        #pragma unroll
        for (int i = 0; i < 3; ++i) {
            r0[i] = *(const uint4*)(Kf + g0 + 8*i);
            r1[i] = *(const uint4*)(Kf + g0 + E_DIM + 8*i);
        }
    }

    for (int kt = 0; kt < 16; ++kt) {
        __syncthreads();   // previous iteration's K-tile reads complete
        if (stager) {
            #pragma unroll
            for (int i = 0; i < 3; ++i) {
                *(uint4*)&sKh[2*sp  ][dq*24 + 8*i] = r0[i];
                *(uint4*)&sKh[2*sp+1][dq*24 + 8*i] = r1[i];
            }
            const unsigned short* p0 = (const unsigned short*)r0;
            const unsigned short* p1 = (const unsigned short*)r1;
            #pragma unroll
            for (int c = 0; c < 24; ++c) {
                unsigned int pk = (unsigned int)p0[c] | ((unsigned int)p1[c] << 16);
                *(unsigned int*)&sKt[dq*24 + c][2*sp] = pk;
            }
        }
        __syncthreads();   // staging visible

        // prefetch next tile (overlaps with compute below)
        if (stager && kt + 1 < 16) {
            const size_t g0 = ((size_t)(b*S_DIM + key0 + (kt+1)*64 + 2*sp))*E_DIM
                              + h*D_DIM + dq*24;
            #pragma unroll
            for (int i = 0; i < 3; ++i) {
                r0[i] = *(const uint4*)(Kf + g0 + 8*i);
                r1[i] = *(const uint4*)(Kf + g0 + E_DIM + 8*i);
            }
        }

        // ---- S^T = K·Q^T (fp16), D[m=key][n=q] ----
        f32x16 s[2];
        #pragma unroll
        for (int mt = 0; mt < 2; ++mt) {
            f32x16 acc;
            #pragma unroll
            for (int r = 0; r < 16; ++r) acc[r] = 0.f;
            #pragma unroll
            for (int kc = 0; kc < 6; ++kc) {
                f16x8 ah = *(const f16x8*)&sKh[mt*32 + col][kc*16 + half*8];
                acc = MFMA32H(ah, qf[kc], acc);
            }
            s[mt] = acc;
        }

        // ---- online softmax, per-lane state (q = col) ----
        float mx = s[0][0];
        #pragma unroll
        for (int mt = 0; mt < 2; ++mt)
            #pragma unroll
            for (int r = 0; r < 16; ++r) mx = fmaxf(mx, s[mt][r]);
        mx = fmaxf(mx, __shfl_xor(mx, 32));

        float m_new = fmaxf(m_i, mx);
        float alpha = __expf(m_i - m_new);
        m_i = m_new;

        float psum = 0.f;
        #pragma unroll
        for (int mt = 0; mt < 2; ++mt)
            #pragma unroll
            for (int g = 0; g < 4; ++g) {
                float e0 = __expf(s[mt][4*g+0] - m_new);
                float e1 = __expf(s[mt][4*g+1] - m_new);
                float e2 = __expf(s[mt][4*g+2] - m_new);
                float e3 = __expf(s[mt][4*g+3] - m_new);
                psum += e0 + e1 + e2 + e3;
                ushort4 pk;
                pk.x = f2h(e0); pk.y = f2h(e1); pk.z = f2h(e2); pk.w = f2h(e3);
                *(ushort4*)&sPs[w*32 + col][mt*32 + 8*g + 4*half] = pk;
            }
        psum += __shfl_xor(psum, 32);
        l_i = l_i * alpha + psum;

        // rescale O: row q_r = 8g + r + 4*half; state lives at lane q_r
        #pragma unroll
        for (int g = 0; g < 4; ++g)
            #pragma unroll
            for (int r = 0; r < 4; ++r) {
                float ar = __shfl(alpha, 8*g + r + 4*half);
                #pragma unroll
                for (int nt = 0; nt < 3; ++nt) o[nt][4*g + r] *= ar;
            }

        // ---- PV: Ohat[q][e] += P·V (A = own sPs rows, B = sKt) ----
        #pragma unroll
        for (int kc = 0; kc < 4; ++kc) {
            f16x8 pa = *(const f16x8*)&sPs[w*32 + col][kc*16 + half*8];
            #pragma unroll
            for (int nt = 0; nt < 3; ++nt) {
                f16x8 vb = *(const f16x8*)&sKt[nt*32 + col][kc*16 + half*8];
                o[nt] = MFMA32H(pa, vb, o[nt]);
            }
        }
    }

    // ---- epilogue: unnormalized Ohat (fp16) + per-row (m,l) ----
    unsigned short* Ob = (kh ? O1 : O0)
        + ((size_t)(b*S_DIM + q0 + w*32))*E_DIM + h*D_DIM;
    #pragma unroll
    for (int g = 0; g < 4; ++g)
        #pragma unroll
        for (int r = 0; r < 4; ++r) {
            int qr = 8*g + r + 4*half;
            #pragma unroll
            for (int nt = 0; nt < 3; ++nt)
                Ob[(size_t)qr*E_DIM + nt*32 + col] = f2h(o[nt][4*g + r]);
        }
    if (lane < 32) {
        int q = q0 + w*32 + lane;
        ml[((size_t)(kh*B_DIM + b)*H_DIM + h)*S_DIM + q] = make_float2(m_i, l_i);
    }
}

// ---------------------------------------------------------------------------
// Merge the two key-half partials -> fp16 context (SCALE applied here)
// ---------------------------------------------------------------------------
__global__ __launch_bounds__(256) void combine_kernel(
    const unsigned short* __restrict__ O0, const unsigned short* __restrict__ O1,
    const float2* __restrict__ ml, unsigned short* __restrict__ ctx)
{
    size_t idx = ((size_t)blockIdx.x * 256 + threadIdx.x) * 4;
    int row = (int)(idx / E_DIM);
    int ce  = (int)(idx % E_DIM);
    int h   = ce / D_DIM;
    int b   = row >> 11;
    int q   = row & (S_DIM - 1);

    float2 m0 = ml[((size_t)(0*B_DIM + b)*H_DIM + h)*S_DIM + q];
    float2 m1 = ml[((size_t)(1*B_DIM + b)*H_DIM + h)*S_DIM + q];
    float m  = fmaxf(m0.x, m1.x);
    float w0 = __expf(m0.x - m), w1 = __expf(m1.x - m);
    float l  = m0.y * w0 + m1.y * w1;
    float s0 = w0 * SCALE_F / l, s1 = w1 * SCALE_F / l;

    ushort4 a = *(const ushort4*)(O0 + idx);
    ushort4 c = *(const ushort4*)(O1 + idx);
    ushort4 o;
    o.x = f2h((float)__builtin_bit_cast(_Float16, a.x)*s0 + (float)__builtin_bit_cast(_Float16, c.x)*s1);
    o.y = f2h((float)__builtin_bit_cast(_Float16, a.y)*s0 + (float)__builtin_bit_cast(_Float16, c.y)*s1);
    o.z = f2h((float)__builtin_bit_cast(_Float16, a.z)*s0 + (float)__builtin_bit_cast(_Float16, c.z)*s1);
    o.w = f2h((float)__builtin_bit_cast(_Float16, a.w)*s0 + (float)__builtin_bit_cast(_Float16, c.w)*s1);
    *(ushort4*)(ctx + idx) = o;
}

// ---------------------------------------------------------------------------
extern "C" void kernel_launch(void* const* d_in, const int* in_sizes, int n_in,
                              void* d_out, int out_size, void* d_ws, size_t ws_size,
                              hipStream_t stream)
{
    const float* x  = (const float*)d_in[0];
    const float* Wq = (const float*)d_in[1];
    const float* bq = (const float*)d_in[2];
    const float* Wk = (const float*)d_in[3];
    const float* bk = (const float*)d_in[4];
    const float* Wo = (const float*)d_in[5];
    const float* bo = (const float*)d_in[6];
    float* out = (float*)d_out;

    const size_t NE = (size_t)M_DIM * E_DIM;        // 3.1M elems
    const size_t WE = (size_t)E_DIM * E_DIM;        // 590K elems
    unsigned short* xf   = (unsigned short*)d_ws;   // NE (aliased Oh0 later)
    unsigned short* WqkT = xf + NE;                 // 2*WE  [Wq^T | Wk^T] fp16
    unsigned short* WoT  = WqkT + 2*WE;             // WE
    unsigned short* Qf   = WoT + WE;                // NE
    unsigned short* Kf   = Qf + NE;                 // NE
    unsigned short* ctx  = Kf + NE;                 // NE
    float2*         mlbuf = (float2*)(ctx + NE);    // 2*B*H*S float2 = 512 KB
    unsigned short* Oh0  = xf;                      // alias: x dead after gemm_qk
    unsigned short* Oh1  = (unsigned short*)d_out;  // overwritten by gemm_out later

    dim3 blk(256);
    hipLaunchKernelGGL(convert_x_kernel, dim3(NE/1024), blk, 0, stream, x, xf);
    hipLaunchKernelGGL(convert_wT3_kernel, dim3(12,12,3), blk, 0, stream,
                       Wq, Wk, Wo, WqkT, WqkT + WE, WoT);

    hipLaunchKernelGGL(gemm_qk_kernel, dim3(12,32), blk, 0, stream,
                       xf, WqkT, bq, bk, Qf, Kf);

    hipLaunchKernelGGL(attn_mfma_kernel, dim3(S_DIM/128, H_DIM, B_DIM*2), blk, 0,
                       stream, Qf, Kf, Oh0, Oh1, mlbuf);

    hipLaunchKernelGGL(combine_kernel, dim3(NE/1024), blk, 0, stream,
                       Oh0, Oh1, mlbuf, ctx);

    hipLaunchKernelGGL(gemm_out_kernel, dim3(12,32), blk, 0, stream,
                       ctx, WoT, bo, out);
}